// Round 8
// baseline (76.456 us; speedup 1.0000x reference)
//
#include <hip/hip_runtime.h>
#include <math.h>

#define GRIDN 64
#define MAXE 32
#define MAXPRIM 1024
#define EROW 36        // parent row: [cnt, e0..e31, pad x3]
#define SCAP2 15
#define SENTV 0xFFFF

// workspace layout (bytes)
#define WS_PACKED2   0u            // 1024*32
#define WS_COLORS    32768u        // 1024*16
#define WS_ETAB      49152u        // 4096*36*4 = 589824 -> ends 638976
#define WS_FLAG      638976u       // 4 B: nonzero if any opacity != 1
#define WS_SUBTAB    655360u       // 65536*32 = 2 MB -> ends 2752512

// exact core: t = rn(td/denom) (double-recip mul), s2 <= Tf <=> rn(sqrt(s2)) <= w
#define CORE_EVAL(A, Bv)                                                         \
    float relx = __fsub_rn(px, A.x);                                             \
    float rely = __fsub_rn(py, A.y);                                             \
    float td = __fadd_rn(__fmul_rn(relx, A.z), __fmul_rn(rely, A.w));            \
    double inv = __hiloint2double(__float_as_int(Bv.z), __float_as_int(Bv.y));   \
    float tt = (float)((double)td * inv);                                        \
    tt = fminf(fmaxf(tt, 0.0f), 1.0f);                                           \
    float qx = __fsub_rn(relx, __fmul_rn(tt, A.z));                              \
    float qy = __fsub_rn(rely, __fmul_rn(tt, A.w));                              \
    float s2 = __fadd_rn(__fmul_rn(qx, qx), __fmul_rn(qy, qy));

// ---------------------------------------------------------------------------
// Kernel 1: prep — parent grid build; block 0 packs prim records and the
// "any opacity != 1" flag.  packed2[p*2+1] = (Tf, inv_lo, inv_hi, w).
// ---------------------------------------------------------------------------
__global__ __launch_bounds__(1024) void prep(const float* __restrict__ cp,
                                             const float* __restrict__ sw,
                                             const float* __restrict__ fc,
                                             const float* __restrict__ op,
                                             float4* __restrict__ packed2,
                                             float4* __restrict__ colors,
                                             int* __restrict__ etab,
                                             int* __restrict__ flagp, int nprim) {
    __shared__ float4 saabb[MAXPRIM];
    __shared__ int sbad;
    int tid = threadIdx.x;
    if (tid == 0) sbad = 0;
    for (int p = tid; p < nprim; p += 1024) {
        float x0 = cp[p * 6 + 0], y0 = cp[p * 6 + 1];
        float x1 = cp[p * 6 + 2], y1 = cp[p * 6 + 3];
        float w = sw[p];
        saabb[p] = make_float4(__fsub_rn(fminf(x0, x1), w), __fadd_rn(fmaxf(x0, x1), w),
                               __fsub_rn(fminf(y0, y1), w), __fadd_rn(fmaxf(y0, y1), w));
    }
    __syncthreads();

    int wid = tid >> 6, lane = tid & 63;
    int cell = blockIdx.x * 16 + wid;
    int ixc = cell >> 6, iyc = cell & 63;
    float lox = (float)ixc * (1.0f / GRIDN);
    float hix = (float)(ixc + 1) * (1.0f / GRIDN);
    float loy = (float)iyc * (1.0f / GRIDN);
    float hiy = (float)(iyc + 1) * (1.0f / GRIDN);
    int total = 0;
    int* row = etab + (size_t)cell * EROW;
    for (int base = 0; base < nprim; base += 64) {
        int p = base + lane;
        bool ov = false;
        if (p < nprim) {
            float4 bb = saabb[p];
            ov = (bb.x < hix) && (bb.y >= lox) && (bb.z < hiy) && (bb.w >= loy);
        }
        unsigned long long m = __ballot(ov);
        if (ov) {
            int pos = total + (int)__popcll(m & ((1ull << lane) - 1ull));
            if (pos < MAXE) row[1 + pos] = p;
        }
        total += (int)__popcll(m);
    }
    if (lane == 0) row[0] = total < MAXE ? total : MAXE;

    if (blockIdx.x == 0) {
        bool bad = false;
        for (int p = tid; p < nprim; p += 1024) {
            float x0 = cp[p * 6 + 0], y0 = cp[p * 6 + 1];
            float x1 = cp[p * 6 + 2], y1 = cp[p * 6 + 3];
            float w = sw[p];
            float dx = __fsub_rn(x1, x0);
            float dy = __fsub_rn(y1, y0);
            float dd = __fadd_rn(__fmul_rn(dx, dx), __fmul_rn(dy, dy));
            float denom = fmaxf(dd, 1e-12f);
            double inv = 1.0 / (double)denom;
            unsigned wb = __float_as_uint(w);
            bool even = (wb & 1u) == 0u;
            float wn = __uint_as_float(wb + 1u);
            double md = 0.5 * ((double)w + (double)wn);
            double m2 = md * md;
            float Tf = (float)m2;
            if ((double)Tf > m2) Tf = __uint_as_float(__float_as_uint(Tf) - 1u);
            if (!even && (double)Tf == m2) Tf = __uint_as_float(__float_as_uint(Tf) - 1u);
            unsigned long long ib = __double_as_longlong(inv);
            packed2[p * 2 + 0] = make_float4(x0, y0, dx, dy);
            packed2[p * 2 + 1] = make_float4(Tf,
                                             __uint_as_float((unsigned)(ib & 0xffffffffull)),
                                             __uint_as_float((unsigned)(ib >> 32)),
                                             w);
            float opv = op[p];
            colors[p] = make_float4(fc[p * 3 + 0], fc[p * 3 + 1], fc[p * 3 + 2], opv);
            if (opv != 1.0f) bad = true;
        }
        if (bad) atomicOr(&sbad, 1);
        __syncthreads();
        if (tid == 0) flagp[0] = sbad;
    }
}

// ---------------------------------------------------------------------------
// Kernel 2: build 256x256 subgrid, exact capsule culling (f64 slab test of
// segment vs subcell rect dilated by w + 1e-5). Row: u16 cnt | 15 u16 (32 B).
// ---------------------------------------------------------------------------
__global__ __launch_bounds__(1024) void build_sub(const float4* __restrict__ packed2,
                                                  const int* __restrict__ etab,
                                                  unsigned short* __restrict__ subtab) {
    int t = blockIdx.x * 1024 + threadIdx.x;
    int parent = t >> 4;
    int sub = t & 15;
    int ix = parent >> 6, iy = parent & 63;
    int gx = ix * 4 + (sub >> 2), gy = iy * 4 + (sub & 3);
    double clx = (double)gx * (1.0 / 256.0);
    double chx = (double)(gx + 1) * (1.0 / 256.0);
    double cly = (double)gy * (1.0 / 256.0);
    double chy = (double)(gy + 1) * (1.0 / 256.0);
    const int* row = etab + (size_t)parent * EROW;
    int cnt = row[0];
    unsigned short* srow = subtab + (size_t)(gx * 256 + gy) * 16;
    int oc = 0;
    for (int s = 0; s < cnt; ++s) {
        int e = row[1 + s];
        float4 A = packed2[e * 2 + 0];
        float4 B = packed2[e * 2 + 1];
        double W = (double)B.w + 1e-5;
        double lx = clx - W, hx = chx + W, ly = cly - W, hy = chy + W;
        double ax = (double)A.x, ay = (double)A.y;
        double dx = (double)A.z, dy = (double)A.w;
        double t0 = 0.0, t1 = 1.0;
        bool ok = true;
        if (fabs(dx) > 1e-300) {
            double ta = (lx - ax) / dx, tb = (hx - ax) / dx;
            t0 = fmax(t0, fmin(ta, tb));
            t1 = fmin(t1, fmax(ta, tb));
        } else if (ax < lx || ax > hx) ok = false;
        if (ok) {
            if (fabs(dy) > 1e-300) {
                double ta = (ly - ay) / dy, tb = (hy - ay) / dy;
                t0 = fmax(t0, fmin(ta, tb));
                t1 = fmin(t1, fmax(ta, tb));
            } else if (ay < ly || ay > hy) ok = false;
        }
        if (ok && t0 <= t1) {
            if (oc < SCAP2) srow[1 + oc] = (unsigned short)e;
            ++oc;
        }
    }
    srow[0] = (oc <= SCAP2) ? (unsigned short)oc : (unsigned short)SENTV;
}

// per-prim test; colors from GLOBAL (only touched in composite path / winner)
__device__ __forceinline__ void test_prim(int e, float px, float py, bool fast,
                                          int& win, float& cr, float& cg, float& cb,
                                          const float4* sA, const float4* sBsk,
                                          const float4* __restrict__ colors) {
    float4 A = sA[e];
    float4 Bv = sBsk[e + 4];
    CORE_EVAL(A, Bv);
    if (fast) {
        if (s2 <= Bv.x) win = e;
    } else {
        float4 C = colors[e];
        float a = (s2 <= Bv.x) ? C.w : 0.0f;
        float om = __fsub_rn(1.0f, a);
        cr = __fadd_rn(__fmul_rn(cr, om), __fmul_rn(C.x, a));
        cg = __fadd_rn(__fmul_rn(cg, om), __fmul_rn(C.y, a));
        cb = __fadd_rn(__fmul_rn(cb, om), __fmul_rn(C.z, a));
    }
}

// ---------------------------------------------------------------------------
// Kernel 3: render with block-local counting sort by per-point slot count.
// 2048 points/block. Sorted processing makes wave slot-count uniform.
// ---------------------------------------------------------------------------
__global__ __launch_bounds__(1024) void render_sorted(const float4* __restrict__ xs4,
                                                      const float4* __restrict__ packed2,
                                                      const float4* __restrict__ colors,
                                                      const int* __restrict__ etab,
                                                      const int* __restrict__ subtab,
                                                      const float* __restrict__ bg,
                                                      const int* __restrict__ flagp,
                                                      float* __restrict__ out,
                                                      int n, int nprim) {
    __shared__ float4 sA[MAXPRIM];
    __shared__ float4 sBsk[MAXPRIM + 4];
    __shared__ float2 spt[2048];
    __shared__ unsigned short perm[2048];
    __shared__ int histw[32][17];   // per-wave bucket counts -> excl. scan
    __shared__ int htot[17];
    __shared__ int pref[17];

    int tid = threadIdx.x;
    int wid = tid >> 6;
    if (tid < 544) ((int*)histw)[tid] = 0;
    __syncthreads();

    int base = blockIdx.x * 2048;
    int nv = n - base;
    nv = nv < 0 ? 0 : (nv > 2048 ? 2048 : nv);

    // stage prim tables (B skewed +64B vs A)
    for (int t = tid; t < nprim; t += 1024) {
        sA[t] = packed2[t * 2 + 0];
        sBsk[t + 4] = packed2[t * 2 + 1];
    }

    // ---- phase 1: read points, bucket by slot count (per-wave histograms) ----
    float4 P = make_float4(0.f, 0.f, 0.f, 0.f);
    int li0 = tid * 2, li1 = tid * 2 + 1;
    if (li1 < nv) {
        P = xs4[blockIdx.x * 1024 + tid];
    } else if (li0 < nv) {
        float2 t2 = ((const float2*)xs4)[base + li0];
        P.x = t2.x; P.y = t2.y;
    }
    int buckj[2], rankj[2];
#pragma unroll
    for (int j = 0; j < 2; ++j) {
        int li = tid * 2 + j;
        buckj[j] = -1; rankj[j] = 0;
        if (li < nv) {
            float px = j ? P.z : P.x;
            float py = j ? P.w : P.y;
            spt[li] = make_float2(px, py);
            int ix = (int)__fmul_rn(px, (float)GRIDN);
            ix = min(max(ix, 0), GRIDN - 1);
            int iy = (int)__fmul_rn(py, (float)GRIDN);
            iy = min(max(iy, 0), GRIDN - 1);
            int sx = (int)__fmul_rn(px, 256.0f) - ix * 4; sx = min(max(sx, 0), 3);
            int sy = (int)__fmul_rn(py, 256.0f) - iy * 4; sy = min(max(sy, 0), 3);
            const unsigned short* sr =
                (const unsigned short*)subtab + (size_t)((ix * 4 + sx) * 256 + (iy * 4 + sy)) * 16;
            int cnt = sr[0];
            int b = cnt > 16 ? 16 : cnt;
            buckj[j] = b;
            rankj[j] = atomicAdd(&histw[wid][b], 1);
        }
    }
    __syncthreads();
    // ---- phase 2: scans ----
    if (tid < 17) {               // exclusive scan over waves, per bucket
        int s = 0;
        for (int w2 = 0; w2 < 32; ++w2) {
            int v = histw[w2][tid];
            histw[w2][tid] = s;
            s += v;
        }
        htot[tid] = s;
    }
    __syncthreads();
    if (tid == 0) {               // exclusive scan over buckets
        int s = 0;
        for (int b = 0; b < 17; ++b) { pref[b] = s; s += htot[b]; }
    }
    __syncthreads();
#pragma unroll
    for (int j = 0; j < 2; ++j) {
        if (buckj[j] >= 0) {
            int pos = pref[buckj[j]] + histw[wid][buckj[j]] + rankj[j];
            perm[pos] = (unsigned short)(tid * 2 + j);
        }
    }
    __syncthreads();

    // ---- phase 3: process in sorted order ----
    bool fast = (flagp[0] == 0);
    float bgr = bg[0], bgg = bg[1], bgb = bg[2];

#pragma unroll
    for (int q = 0; q < 2; ++q) {
        int pos = tid + q * 1024;
        if (pos >= nv) continue;
        int li = perm[pos];
        float2 pp = spt[li];
        float px = pp.x, py = pp.y;
        int ix = (int)__fmul_rn(px, (float)GRIDN);
        ix = min(max(ix, 0), GRIDN - 1);
        int iy = (int)__fmul_rn(py, (float)GRIDN);
        iy = min(max(iy, 0), GRIDN - 1);
        int sx = (int)__fmul_rn(px, 256.0f) - ix * 4; sx = min(max(sx, 0), 3);
        int sy = (int)__fmul_rn(py, 256.0f) - iy * 4; sy = min(max(sy, 0), 3);
        const int* srow = subtab + (size_t)((ix * 4 + sx) * 256 + (iy * 4 + sy)) * 8;
        int4 lo = *(const int4*)srow;
        int4 hi = *(const int4*)(srow + 4);
        float cr = bgr, cg = bgg, cb = bgb;
        int win = -1;
        unsigned w0 = (unsigned)lo.x;
        int cnt = (int)(w0 & 0xffffu);
        if (cnt != SENTV) {
            unsigned wy = (unsigned)lo.y, wz = (unsigned)lo.z, ww = (unsigned)lo.w;
            unsigned hx = (unsigned)hi.x, hy = (unsigned)hi.y;
            unsigned hz = (unsigned)hi.z, hw = (unsigned)hi.w;
            if (cnt > 0)  test_prim((int)(w0 >> 16),     px, py, fast, win, cr, cg, cb, sA, sBsk, colors);
            if (cnt > 1)  test_prim((int)(wy & 0xffffu), px, py, fast, win, cr, cg, cb, sA, sBsk, colors);
            if (cnt > 2)  test_prim((int)(wy >> 16),     px, py, fast, win, cr, cg, cb, sA, sBsk, colors);
            if (cnt > 3)  test_prim((int)(wz & 0xffffu), px, py, fast, win, cr, cg, cb, sA, sBsk, colors);
            if (cnt > 4)  test_prim((int)(wz >> 16),     px, py, fast, win, cr, cg, cb, sA, sBsk, colors);
            if (cnt > 5)  test_prim((int)(ww & 0xffffu), px, py, fast, win, cr, cg, cb, sA, sBsk, colors);
            if (cnt > 6)  test_prim((int)(ww >> 16),     px, py, fast, win, cr, cg, cb, sA, sBsk, colors);
            if (cnt > 7)  test_prim((int)(hx & 0xffffu), px, py, fast, win, cr, cg, cb, sA, sBsk, colors);
            if (cnt > 8)  test_prim((int)(hx >> 16),     px, py, fast, win, cr, cg, cb, sA, sBsk, colors);
            if (cnt > 9)  test_prim((int)(hy & 0xffffu), px, py, fast, win, cr, cg, cb, sA, sBsk, colors);
            if (cnt > 10) test_prim((int)(hy >> 16),     px, py, fast, win, cr, cg, cb, sA, sBsk, colors);
            if (cnt > 11) test_prim((int)(hz & 0xffffu), px, py, fast, win, cr, cg, cb, sA, sBsk, colors);
            if (cnt > 12) test_prim((int)(hz >> 16),     px, py, fast, win, cr, cg, cb, sA, sBsk, colors);
            if (cnt > 13) test_prim((int)(hw & 0xffffu), px, py, fast, win, cr, cg, cb, sA, sBsk, colors);
            if (cnt > 14) test_prim((int)(hw >> 16),     px, py, fast, win, cr, cg, cb, sA, sBsk, colors);
        } else {
            const int* prow = etab + (size_t)(ix * GRIDN + iy) * EROW;
            int pcnt = prow[0];
            for (int s = 0; s < pcnt; ++s)
                test_prim(prow[1 + s], px, py, fast, win, cr, cg, cb, sA, sBsk, colors);
        }
        if (fast && win >= 0) {
            float4 C = colors[win];
            cr = C.x; cg = C.y; cb = C.z;
        }
        float* ob = out + (size_t)(base + li) * 3;
        ob[0] = cr; ob[1] = cg; ob[2] = cb;
    }
}

// ---------------------------------------------------------------------------
// Fallback render (round-4 style) if ws_size too small for the subgrid.
// ---------------------------------------------------------------------------
__global__ __launch_bounds__(1024) void render_fb(const float2* __restrict__ xs,
                                                  const float4* __restrict__ packed2,
                                                  const float4* __restrict__ colors,
                                                  const int* __restrict__ etab,
                                                  const float* __restrict__ bg,
                                                  float* __restrict__ out, int n, int nprim) {
    __shared__ float4 sA[MAXPRIM];
    __shared__ float4 sBsk[MAXPRIM + 4];
    __shared__ int sflag;
    if (threadIdx.x == 0) sflag = 0;
    __syncthreads();

    int i = blockIdx.x * 1024 + threadIdx.x;
    bool valid = i < n;
    float px = 0.0f, py = 0.0f;
    int row = 0;
    int4 c0 = make_int4(0, 0, 0, 0), c1 = make_int4(0, 0, 0, 0);
    if (valid) {
        float2 pxy = xs[i];
        px = pxy.x; py = pxy.y;
        int ix = (int)__fmul_rn(px, (float)GRIDN);
        ix = min(max(ix, 0), GRIDN - 1);
        int iy = (int)__fmul_rn(py, (float)GRIDN);
        iy = min(max(iy, 0), GRIDN - 1);
        row = (ix * GRIDN + iy) * EROW;
        c0 = *(const int4*)(etab + row);
        c1 = *(const int4*)(etab + row + 4);
    }
    for (int t = threadIdx.x; t < nprim; t += 1024) {
        sA[t] = packed2[t * 2 + 0];
        sBsk[t + 4] = packed2[t * 2 + 1];
        if (colors[t].w != 1.0f) sflag = 1;
    }
    __syncthreads();
    int cnt = valid ? c0.x : 0;
    float cr = bg[0], cg = bg[1], cb = bg[2];
    int win = -1;
    bool fast = (sflag == 0);
    if (cnt > 0) test_prim(c0.y, px, py, fast, win, cr, cg, cb, sA, sBsk, colors);
    if (cnt > 1) test_prim(c0.z, px, py, fast, win, cr, cg, cb, sA, sBsk, colors);
    if (cnt > 2) test_prim(c0.w, px, py, fast, win, cr, cg, cb, sA, sBsk, colors);
    if (cnt > 3) test_prim(c1.x, px, py, fast, win, cr, cg, cb, sA, sBsk, colors);
    if (cnt > 4) test_prim(c1.y, px, py, fast, win, cr, cg, cb, sA, sBsk, colors);
    if (cnt > 5) test_prim(c1.z, px, py, fast, win, cr, cg, cb, sA, sBsk, colors);
    if (cnt > 6) test_prim(c1.w, px, py, fast, win, cr, cg, cb, sA, sBsk, colors);
    for (int base = 7; base < cnt; base += 4) {
        int4 c = *(const int4*)(etab + row + 1 + base);
        if (base + 0 < cnt) test_prim(c.x, px, py, fast, win, cr, cg, cb, sA, sBsk, colors);
        if (base + 1 < cnt) test_prim(c.y, px, py, fast, win, cr, cg, cb, sA, sBsk, colors);
        if (base + 2 < cnt) test_prim(c.z, px, py, fast, win, cr, cg, cb, sA, sBsk, colors);
        if (base + 3 < cnt) test_prim(c.w, px, py, fast, win, cr, cg, cb, sA, sBsk, colors);
    }
    if (valid) {
        if (fast && win >= 0) {
            float4 C = colors[win];
            cr = C.x; cg = C.y; cb = C.z;
        }
        out[(size_t)i * 3 + 0] = cr;
        out[(size_t)i * 3 + 1] = cg;
        out[(size_t)i * 3 + 2] = cb;
    }
}

extern "C" void kernel_launch(void* const* d_in, const int* in_sizes, int n_in,
                              void* d_out, int out_size, void* d_ws, size_t ws_size,
                              hipStream_t stream) {
    const float* x  = (const float*)d_in[0];
    const float* cp = (const float*)d_in[1];
    const float* sw = (const float*)d_in[2];
    const float* fc = (const float*)d_in[3];
    const float* op = (const float*)d_in[4];
    const float* bg = (const float*)d_in[5];
    float* out = (float*)d_out;

    int npts  = in_sizes[0] / 2;
    int nprim = in_sizes[2];

    char* ws = (char*)d_ws;
    float4* packed2 = (float4*)(ws + WS_PACKED2);
    float4* colors  = (float4*)(ws + WS_COLORS);
    int* etab       = (int*)(ws + WS_ETAB);
    int* flagp      = (int*)(ws + WS_FLAG);
    unsigned short* subtab = (unsigned short*)(ws + WS_SUBTAB);

    size_t need = (size_t)WS_SUBTAB + 65536u * 32u;
    bool use_sub = (ws_size >= need);

    prep<<<GRIDN * GRIDN / 16, 1024, 0, stream>>>(cp, sw, fc, op, packed2, colors,
                                                  etab, flagp, nprim);
    if (use_sub) {
        build_sub<<<64, 1024, 0, stream>>>(packed2, etab, subtab);
        int nblk = (npts + 2047) / 2048;
        render_sorted<<<nblk, 1024, 0, stream>>>((const float4*)x, packed2, colors,
                                                 etab, (const int*)subtab, bg, flagp,
                                                 out, npts, nprim);
    } else {
        render_fb<<<(npts + 1023) / 1024, 1024, 0, stream>>>((const float2*)x, packed2,
                                                             colors, etab, bg, out,
                                                             npts, nprim);
    }
}

// Round 9
// 63.330 us; speedup vs baseline: 1.2073x; 1.2073x over previous
//
#include <hip/hip_runtime.h>
#include <math.h>

#define GRIDN 64
#define MAXE 32
#define MAXPRIM 1024
#define EROW 36        // parent row: [cnt, e0..e31, pad x3]
#define SCAP2 15
#define SENTV 0xFFFF

// workspace layout (bytes)
#define WS_PACKED2   0u            // 1024*32
#define WS_COLORS    32768u        // 1024*16
#define WS_ETAB      49152u        // 4096*36*4 = 589824 -> ends 638976
#define WS_FLAG      638976u       // 4 B: nonzero if any opacity != 1
#define WS_SUBTAB    655360u       // 65536*32 = 2 MB -> ends 2752512

// exact core: t = rn(td/denom) (double-recip mul), s2 <= Tf <=> rn(sqrt(s2)) <= w
#define CORE_EVAL(A, Bv)                                                         \
    float relx = __fsub_rn(px, A.x);                                             \
    float rely = __fsub_rn(py, A.y);                                             \
    float td = __fadd_rn(__fmul_rn(relx, A.z), __fmul_rn(rely, A.w));            \
    double inv = __hiloint2double(__float_as_int(Bv.z), __float_as_int(Bv.y));   \
    float tt = (float)((double)td * inv);                                        \
    tt = fminf(fmaxf(tt, 0.0f), 1.0f);                                           \
    float qx = __fsub_rn(relx, __fmul_rn(tt, A.z));                              \
    float qy = __fsub_rn(rely, __fmul_rn(tt, A.w));                              \
    float s2 = __fadd_rn(__fmul_rn(qx, qx), __fmul_rn(qy, qy));

// ---------------------------------------------------------------------------
// Kernel 1: prep — parent grid build; block 0 packs prim records and the
// "any opacity != 1" flag.  packed2[p*2+1] = (Tf, inv_lo, inv_hi, w).
// ---------------------------------------------------------------------------
__global__ __launch_bounds__(1024) void prep(const float* __restrict__ cp,
                                             const float* __restrict__ sw,
                                             const float* __restrict__ fc,
                                             const float* __restrict__ op,
                                             float4* __restrict__ packed2,
                                             float4* __restrict__ colors,
                                             int* __restrict__ etab,
                                             int* __restrict__ flagp, int nprim) {
    __shared__ float4 saabb[MAXPRIM];
    __shared__ int sbad;
    int tid = threadIdx.x;
    if (tid == 0) sbad = 0;
    for (int p = tid; p < nprim; p += 1024) {
        float x0 = cp[p * 6 + 0], y0 = cp[p * 6 + 1];
        float x1 = cp[p * 6 + 2], y1 = cp[p * 6 + 3];
        float w = sw[p];
        saabb[p] = make_float4(__fsub_rn(fminf(x0, x1), w), __fadd_rn(fmaxf(x0, x1), w),
                               __fsub_rn(fminf(y0, y1), w), __fadd_rn(fmaxf(y0, y1), w));
    }
    __syncthreads();

    int wid = tid >> 6, lane = tid & 63;
    int cell = blockIdx.x * 16 + wid;
    int ixc = cell >> 6, iyc = cell & 63;
    float lox = (float)ixc * (1.0f / GRIDN);
    float hix = (float)(ixc + 1) * (1.0f / GRIDN);
    float loy = (float)iyc * (1.0f / GRIDN);
    float hiy = (float)(iyc + 1) * (1.0f / GRIDN);
    int total = 0;
    int* row = etab + (size_t)cell * EROW;
    for (int base = 0; base < nprim; base += 64) {
        int p = base + lane;
        bool ov = false;
        if (p < nprim) {
            float4 bb = saabb[p];
            ov = (bb.x < hix) && (bb.y >= lox) && (bb.z < hiy) && (bb.w >= loy);
        }
        unsigned long long m = __ballot(ov);
        if (ov) {
            int pos = total + (int)__popcll(m & ((1ull << lane) - 1ull));
            if (pos < MAXE) row[1 + pos] = p;
        }
        total += (int)__popcll(m);
    }
    if (lane == 0) row[0] = total < MAXE ? total : MAXE;

    if (blockIdx.x == 0) {
        bool bad = false;
        for (int p = tid; p < nprim; p += 1024) {
            float x0 = cp[p * 6 + 0], y0 = cp[p * 6 + 1];
            float x1 = cp[p * 6 + 2], y1 = cp[p * 6 + 3];
            float w = sw[p];
            float dx = __fsub_rn(x1, x0);
            float dy = __fsub_rn(y1, y0);
            float dd = __fadd_rn(__fmul_rn(dx, dx), __fmul_rn(dy, dy));
            float denom = fmaxf(dd, 1e-12f);
            double inv = 1.0 / (double)denom;
            unsigned wb = __float_as_uint(w);
            bool even = (wb & 1u) == 0u;
            float wn = __uint_as_float(wb + 1u);
            double md = 0.5 * ((double)w + (double)wn);
            double m2 = md * md;
            float Tf = (float)m2;
            if ((double)Tf > m2) Tf = __uint_as_float(__float_as_uint(Tf) - 1u);
            if (!even && (double)Tf == m2) Tf = __uint_as_float(__float_as_uint(Tf) - 1u);
            unsigned long long ib = __double_as_longlong(inv);
            packed2[p * 2 + 0] = make_float4(x0, y0, dx, dy);
            packed2[p * 2 + 1] = make_float4(Tf,
                                             __uint_as_float((unsigned)(ib & 0xffffffffull)),
                                             __uint_as_float((unsigned)(ib >> 32)),
                                             w);
            float opv = op[p];
            colors[p] = make_float4(fc[p * 3 + 0], fc[p * 3 + 1], fc[p * 3 + 2], opv);
            if (opv != 1.0f) bad = true;
        }
        if (bad) atomicOr(&sbad, 1);
        __syncthreads();
        if (tid == 0) flagp[0] = sbad;
    }
}

// ---------------------------------------------------------------------------
// Kernel 2: build 256x256 subgrid, exact capsule culling (f64 slab test of
// segment vs subcell rect dilated by w + 1e-5). Row: u16 cnt | 15 u16 (32 B).
// ---------------------------------------------------------------------------
__global__ __launch_bounds__(1024) void build_sub(const float4* __restrict__ packed2,
                                                  const int* __restrict__ etab,
                                                  unsigned short* __restrict__ subtab) {
    int t = blockIdx.x * 1024 + threadIdx.x;
    int parent = t >> 4;
    int sub = t & 15;
    int ix = parent >> 6, iy = parent & 63;
    int gx = ix * 4 + (sub >> 2), gy = iy * 4 + (sub & 3);
    double clx = (double)gx * (1.0 / 256.0);
    double chx = (double)(gx + 1) * (1.0 / 256.0);
    double cly = (double)gy * (1.0 / 256.0);
    double chy = (double)(gy + 1) * (1.0 / 256.0);
    const int* row = etab + (size_t)parent * EROW;
    int cnt = row[0];
    unsigned short* srow = subtab + (size_t)(gx * 256 + gy) * 16;
    int oc = 0;
    for (int s = 0; s < cnt; ++s) {
        int e = row[1 + s];
        float4 A = packed2[e * 2 + 0];
        float4 B = packed2[e * 2 + 1];
        double W = (double)B.w + 1e-5;
        double lx = clx - W, hx = chx + W, ly = cly - W, hy = chy + W;
        double ax = (double)A.x, ay = (double)A.y;
        double dx = (double)A.z, dy = (double)A.w;
        double t0 = 0.0, t1 = 1.0;
        bool ok = true;
        if (fabs(dx) > 1e-300) {
            double ta = (lx - ax) / dx, tb = (hx - ax) / dx;
            t0 = fmax(t0, fmin(ta, tb));
            t1 = fmin(t1, fmax(ta, tb));
        } else if (ax < lx || ax > hx) ok = false;
        if (ok) {
            if (fabs(dy) > 1e-300) {
                double ta = (ly - ay) / dy, tb = (hy - ay) / dy;
                t0 = fmax(t0, fmin(ta, tb));
                t1 = fmin(t1, fmax(ta, tb));
            } else if (ay < ly || ay > hy) ok = false;
        }
        if (ok && t0 <= t1) {
            if (oc < SCAP2) srow[1 + oc] = (unsigned short)e;
            ++oc;
        }
    }
    srow[0] = (oc <= SCAP2) ? (unsigned short)oc : (unsigned short)SENTV;
}

// per-prim test; colors from GLOBAL (only touched on composite path)
__device__ __forceinline__ void test_prim(int e, float px, float py, bool fast,
                                          int& win, float& cr, float& cg, float& cb,
                                          const float4* sA, const float4* sBsk,
                                          const float4* __restrict__ colors) {
    float4 A = sA[e];
    float4 Bv = sBsk[e + 4];
    CORE_EVAL(A, Bv);
    if (fast) {
        if (s2 <= Bv.x) win = e;       // ascending order: later = winner
    } else {
        float4 C = colors[e];
        float a = (s2 <= Bv.x) ? C.w : 0.0f;
        float om = __fsub_rn(1.0f, a);
        cr = __fadd_rn(__fmul_rn(cr, om), __fmul_rn(C.x, a));
        cg = __fadd_rn(__fmul_rn(cg, om), __fmul_rn(C.y, a));
        cb = __fadd_rn(__fmul_rn(cb, om), __fmul_rn(C.z, a));
    }
}

// ---------------------------------------------------------------------------
// Kernel 3: render, 4 points per thread (4 independent chains for MLP).
// All 4 subtab taps issued before the staging barrier; 3 coalesced float4
// stores per thread. Prim geometry in LDS (B skewed +64B); colors via L2.
// ---------------------------------------------------------------------------
__global__ __launch_bounds__(512) void render4(const float4* __restrict__ xs4,
                                               const float4* __restrict__ packed2,
                                               const float4* __restrict__ colors,
                                               const int* __restrict__ etab,
                                               const int* __restrict__ subtab,
                                               const float* __restrict__ bg,
                                               const int* __restrict__ flagp,
                                               float* __restrict__ out,
                                               int n, int nprim) {
    __shared__ float4 sA[MAXPRIM];
    __shared__ float4 sBsk[MAXPRIM + 4];

    int tid = threadIdx.x;
    long long g0 = (long long)blockIdx.x * 2048 + (long long)tid * 4;
    bool vall = (g0 + 3) < (long long)n;

    float4 Pa = make_float4(0.f, 0.f, 0.f, 0.f);
    float4 Pb = make_float4(0.f, 0.f, 0.f, 0.f);
    if (vall) {
        Pa = xs4[g0 >> 1];
        Pb = xs4[(g0 >> 1) + 1];
    } else {
        const float2* xs2 = (const float2*)xs4;
        if (g0 + 0 < n) { float2 t0 = xs2[g0 + 0]; Pa.x = t0.x; Pa.y = t0.y; }
        if (g0 + 1 < n) { float2 t1 = xs2[g0 + 1]; Pa.z = t1.x; Pa.w = t1.y; }
        if (g0 + 2 < n) { float2 t2 = xs2[g0 + 2]; Pb.x = t2.x; Pb.y = t2.y; }
        if (g0 + 3 < n) { float2 t3 = xs2[g0 + 3]; Pb.z = t3.x; Pb.w = t3.y; }
    }
    float pxa[4] = {Pa.x, Pa.z, Pb.x, Pb.z};
    float pya[4] = {Pa.y, Pa.w, Pb.y, Pb.w};
    bool vs[4];
    int par[4];
    int4 lo[4], hi[4];

#pragma unroll
    for (int j = 0; j < 4; ++j) {
        vs[j] = (g0 + j) < (long long)n;
        par[j] = 0;
        lo[j] = make_int4(0, 0, 0, 0);
        hi[j] = make_int4(0, 0, 0, 0);
        if (vs[j]) {
            float px = pxa[j], py = pya[j];
            int ix = (int)__fmul_rn(px, (float)GRIDN);
            ix = min(max(ix, 0), GRIDN - 1);
            int iy = (int)__fmul_rn(py, (float)GRIDN);
            iy = min(max(iy, 0), GRIDN - 1);
            par[j] = ix * GRIDN + iy;
            int sx = (int)__fmul_rn(px, 256.0f) - ix * 4; sx = min(max(sx, 0), 3);
            int sy = (int)__fmul_rn(py, 256.0f) - iy * 4; sy = min(max(sy, 0), 3);
            const int* srow = subtab + (size_t)((ix * 4 + sx) * 256 + (iy * 4 + sy)) * 8;
            lo[j] = *(const int4*)srow;
            hi[j] = *(const int4*)(srow + 4);
        }
    }

    for (int t = tid; t < nprim; t += 512) {
        sA[t] = packed2[t * 2 + 0];
        sBsk[t + 4] = packed2[t * 2 + 1];
    }
    __syncthreads();

    bool fast = (flagp[0] == 0);
    float bgr = bg[0], bgg = bg[1], bgb = bg[2];
    float res[12];

#pragma unroll
    for (int j = 0; j < 4; ++j) {
        float px = pxa[j], py = pya[j];
        float cr = bgr, cg = bgg, cb = bgb;
        int win = -1;
        unsigned w0 = (unsigned)lo[j].x;
        int cnt = vs[j] ? (int)(w0 & 0xffffu) : 0;
        if (cnt != SENTV) {
            unsigned wy = (unsigned)lo[j].y, wz = (unsigned)lo[j].z, ww = (unsigned)lo[j].w;
            unsigned hx = (unsigned)hi[j].x, hy = (unsigned)hi[j].y;
            unsigned hz = (unsigned)hi[j].z, hw = (unsigned)hi[j].w;
            if (cnt > 0)  test_prim((int)(w0 >> 16),     px, py, fast, win, cr, cg, cb, sA, sBsk, colors);
            if (cnt > 1)  test_prim((int)(wy & 0xffffu), px, py, fast, win, cr, cg, cb, sA, sBsk, colors);
            if (cnt > 2)  test_prim((int)(wy >> 16),     px, py, fast, win, cr, cg, cb, sA, sBsk, colors);
            if (cnt > 3)  test_prim((int)(wz & 0xffffu), px, py, fast, win, cr, cg, cb, sA, sBsk, colors);
            if (cnt > 4)  test_prim((int)(wz >> 16),     px, py, fast, win, cr, cg, cb, sA, sBsk, colors);
            if (cnt > 5)  test_prim((int)(ww & 0xffffu), px, py, fast, win, cr, cg, cb, sA, sBsk, colors);
            if (cnt > 6)  test_prim((int)(ww >> 16),     px, py, fast, win, cr, cg, cb, sA, sBsk, colors);
            if (cnt > 7)  test_prim((int)(hx & 0xffffu), px, py, fast, win, cr, cg, cb, sA, sBsk, colors);
            if (cnt > 8)  test_prim((int)(hx >> 16),     px, py, fast, win, cr, cg, cb, sA, sBsk, colors);
            if (cnt > 9)  test_prim((int)(hy & 0xffffu), px, py, fast, win, cr, cg, cb, sA, sBsk, colors);
            if (cnt > 10) test_prim((int)(hy >> 16),     px, py, fast, win, cr, cg, cb, sA, sBsk, colors);
            if (cnt > 11) test_prim((int)(hz & 0xffffu), px, py, fast, win, cr, cg, cb, sA, sBsk, colors);
            if (cnt > 12) test_prim((int)(hz >> 16),     px, py, fast, win, cr, cg, cb, sA, sBsk, colors);
            if (cnt > 13) test_prim((int)(hw & 0xffffu), px, py, fast, win, cr, cg, cb, sA, sBsk, colors);
            if (cnt > 14) test_prim((int)(hw >> 16),     px, py, fast, win, cr, cg, cb, sA, sBsk, colors);
        } else {
            const int* prow = etab + (size_t)par[j] * EROW;
            int pcnt = prow[0];
            for (int s = 0; s < pcnt; ++s)
                test_prim(prow[1 + s], px, py, fast, win, cr, cg, cb, sA, sBsk, colors);
        }
        if (fast && win >= 0) {
            float4 C = colors[win];
            cr = C.x; cg = C.y; cb = C.z;
        }
        res[j * 3 + 0] = cr;
        res[j * 3 + 1] = cg;
        res[j * 3 + 2] = cb;
    }

    if (vall) {
        float4* ob = (float4*)(out + g0 * 3);   // byte offset g0*12, 16B-aligned
        ob[0] = make_float4(res[0], res[1], res[2], res[3]);
        ob[1] = make_float4(res[4], res[5], res[6], res[7]);
        ob[2] = make_float4(res[8], res[9], res[10], res[11]);
    } else {
#pragma unroll
        for (int j = 0; j < 4; ++j) {
            if (vs[j]) {
                float* ob = out + (size_t)(g0 + j) * 3;
                ob[0] = res[j * 3 + 0];
                ob[1] = res[j * 3 + 1];
                ob[2] = res[j * 3 + 2];
            }
        }
    }
}

// ---------------------------------------------------------------------------
// Fallback render (round-4 style) if ws_size too small for the subgrid.
// ---------------------------------------------------------------------------
__global__ __launch_bounds__(1024) void render_fb(const float2* __restrict__ xs,
                                                  const float4* __restrict__ packed2,
                                                  const float4* __restrict__ colors,
                                                  const int* __restrict__ etab,
                                                  const float* __restrict__ bg,
                                                  float* __restrict__ out, int n, int nprim) {
    __shared__ float4 sA[MAXPRIM];
    __shared__ float4 sBsk[MAXPRIM + 4];
    __shared__ int sflag;
    if (threadIdx.x == 0) sflag = 0;
    __syncthreads();

    int i = blockIdx.x * 1024 + threadIdx.x;
    bool valid = i < n;
    float px = 0.0f, py = 0.0f;
    int row = 0;
    int4 c0 = make_int4(0, 0, 0, 0), c1 = make_int4(0, 0, 0, 0);
    if (valid) {
        float2 pxy = xs[i];
        px = pxy.x; py = pxy.y;
        int ix = (int)__fmul_rn(px, (float)GRIDN);
        ix = min(max(ix, 0), GRIDN - 1);
        int iy = (int)__fmul_rn(py, (float)GRIDN);
        iy = min(max(iy, 0), GRIDN - 1);
        row = (ix * GRIDN + iy) * EROW;
        c0 = *(const int4*)(etab + row);
        c1 = *(const int4*)(etab + row + 4);
    }
    for (int t = threadIdx.x; t < nprim; t += 1024) {
        sA[t] = packed2[t * 2 + 0];
        sBsk[t + 4] = packed2[t * 2 + 1];
        if (colors[t].w != 1.0f) sflag = 1;
    }
    __syncthreads();
    int cnt = valid ? c0.x : 0;
    float cr = bg[0], cg = bg[1], cb = bg[2];
    int win = -1;
    bool fast = (sflag == 0);
    if (cnt > 0) test_prim(c0.y, px, py, fast, win, cr, cg, cb, sA, sBsk, colors);
    if (cnt > 1) test_prim(c0.z, px, py, fast, win, cr, cg, cb, sA, sBsk, colors);
    if (cnt > 2) test_prim(c0.w, px, py, fast, win, cr, cg, cb, sA, sBsk, colors);
    if (cnt > 3) test_prim(c1.x, px, py, fast, win, cr, cg, cb, sA, sBsk, colors);
    if (cnt > 4) test_prim(c1.y, px, py, fast, win, cr, cg, cb, sA, sBsk, colors);
    if (cnt > 5) test_prim(c1.z, px, py, fast, win, cr, cg, cb, sA, sBsk, colors);
    if (cnt > 6) test_prim(c1.w, px, py, fast, win, cr, cg, cb, sA, sBsk, colors);
    for (int base = 7; base < cnt; base += 4) {
        int4 c = *(const int4*)(etab + row + 1 + base);
        if (base + 0 < cnt) test_prim(c.x, px, py, fast, win, cr, cg, cb, sA, sBsk, colors);
        if (base + 1 < cnt) test_prim(c.y, px, py, fast, win, cr, cg, cb, sA, sBsk, colors);
        if (base + 2 < cnt) test_prim(c.z, px, py, fast, win, cr, cg, cb, sA, sBsk, colors);
        if (base + 3 < cnt) test_prim(c.w, px, py, fast, win, cr, cg, cb, sA, sBsk, colors);
    }
    if (valid) {
        if (fast && win >= 0) {
            float4 C = colors[win];
            cr = C.x; cg = C.y; cb = C.z;
        }
        out[(size_t)i * 3 + 0] = cr;
        out[(size_t)i * 3 + 1] = cg;
        out[(size_t)i * 3 + 2] = cb;
    }
}

extern "C" void kernel_launch(void* const* d_in, const int* in_sizes, int n_in,
                              void* d_out, int out_size, void* d_ws, size_t ws_size,
                              hipStream_t stream) {
    const float* x  = (const float*)d_in[0];
    const float* cp = (const float*)d_in[1];
    const float* sw = (const float*)d_in[2];
    const float* fc = (const float*)d_in[3];
    const float* op = (const float*)d_in[4];
    const float* bg = (const float*)d_in[5];
    float* out = (float*)d_out;

    int npts  = in_sizes[0] / 2;
    int nprim = in_sizes[2];

    char* ws = (char*)d_ws;
    float4* packed2 = (float4*)(ws + WS_PACKED2);
    float4* colors  = (float4*)(ws + WS_COLORS);
    int* etab       = (int*)(ws + WS_ETAB);
    int* flagp      = (int*)(ws + WS_FLAG);
    unsigned short* subtab = (unsigned short*)(ws + WS_SUBTAB);

    size_t need = (size_t)WS_SUBTAB + 65536u * 32u;
    bool use_sub = (ws_size >= need);

    prep<<<GRIDN * GRIDN / 16, 1024, 0, stream>>>(cp, sw, fc, op, packed2, colors,
                                                  etab, flagp, nprim);
    if (use_sub) {
        build_sub<<<64, 1024, 0, stream>>>(packed2, etab, subtab);
        int nblk = (npts + 2047) / 2048;
        render4<<<nblk, 512, 0, stream>>>((const float4*)x, packed2, colors,
                                          etab, (const int*)subtab, bg, flagp,
                                          out, npts, nprim);
    } else {
        render_fb<<<(npts + 1023) / 1024, 1024, 0, stream>>>((const float2*)x, packed2,
                                                             colors, etab, bg, out,
                                                             npts, nprim);
    }
}

// Round 10
// 58.555 us; speedup vs baseline: 1.3057x; 1.0816x over previous
//
#include <hip/hip_runtime.h>
#include <math.h>

#define GRIDN 64
#define MAXE 32
#define MAXPRIM 1024
#define EROW 36        // parent row: [cnt, e0..e31, pad x3]
#define SCAP2 15
#define SENTV 0xFFFF

// workspace layout (bytes)
#define WS_PACKED2   0u            // 1024*32
#define WS_COLORS    32768u        // 1024*16
#define WS_ETAB      49152u        // 4096*36*4 = 589824 -> ends 638976
#define WS_FLAG      638976u       // 4 B: nonzero if any opacity != 1
#define WS_SUBTAB    655360u       // 65536*32 = 2 MB -> ends 2752512

// exact core: t = rn(td/denom) (double-recip mul), s2 <= Tf <=> rn(sqrt(s2)) <= w
#define CORE_EVAL(A, Bv)                                                         \
    float relx = __fsub_rn(px, A.x);                                             \
    float rely = __fsub_rn(py, A.y);                                             \
    float td = __fadd_rn(__fmul_rn(relx, A.z), __fmul_rn(rely, A.w));            \
    double inv = __hiloint2double(__float_as_int(Bv.z), __float_as_int(Bv.y));   \
    float tt = (float)((double)td * inv);                                        \
    tt = fminf(fmaxf(tt, 0.0f), 1.0f);                                           \
    float qx = __fsub_rn(relx, __fmul_rn(tt, A.z));                              \
    float qy = __fsub_rn(rely, __fmul_rn(tt, A.w));                              \
    float s2 = __fadd_rn(__fmul_rn(qx, qx), __fmul_rn(qy, qy));

// ---------------------------------------------------------------------------
// Kernel 1: prep — parent grid build; block 0 packs prim records and the
// "any opacity != 1" flag.  packed2[p*2+1] = (Tf, inv_lo, inv_hi, w).
// ---------------------------------------------------------------------------
__global__ __launch_bounds__(1024) void prep(const float* __restrict__ cp,
                                             const float* __restrict__ sw,
                                             const float* __restrict__ fc,
                                             const float* __restrict__ op,
                                             float4* __restrict__ packed2,
                                             float4* __restrict__ colors,
                                             int* __restrict__ etab,
                                             int* __restrict__ flagp, int nprim) {
    __shared__ float4 saabb[MAXPRIM];
    __shared__ int sbad;
    int tid = threadIdx.x;
    if (tid == 0) sbad = 0;
    for (int p = tid; p < nprim; p += 1024) {
        float x0 = cp[p * 6 + 0], y0 = cp[p * 6 + 1];
        float x1 = cp[p * 6 + 2], y1 = cp[p * 6 + 3];
        float w = sw[p];
        saabb[p] = make_float4(__fsub_rn(fminf(x0, x1), w), __fadd_rn(fmaxf(x0, x1), w),
                               __fsub_rn(fminf(y0, y1), w), __fadd_rn(fmaxf(y0, y1), w));
    }
    __syncthreads();

    int wid = tid >> 6, lane = tid & 63;
    int cell = blockIdx.x * 16 + wid;
    int ixc = cell >> 6, iyc = cell & 63;
    float lox = (float)ixc * (1.0f / GRIDN);
    float hix = (float)(ixc + 1) * (1.0f / GRIDN);
    float loy = (float)iyc * (1.0f / GRIDN);
    float hiy = (float)(iyc + 1) * (1.0f / GRIDN);
    int total = 0;
    int* row = etab + (size_t)cell * EROW;
    for (int base = 0; base < nprim; base += 64) {
        int p = base + lane;
        bool ov = false;
        if (p < nprim) {
            float4 bb = saabb[p];
            ov = (bb.x < hix) && (bb.y >= lox) && (bb.z < hiy) && (bb.w >= loy);
        }
        unsigned long long m = __ballot(ov);
        if (ov) {
            int pos = total + (int)__popcll(m & ((1ull << lane) - 1ull));
            if (pos < MAXE) row[1 + pos] = p;
        }
        total += (int)__popcll(m);
    }
    if (lane == 0) row[0] = total < MAXE ? total : MAXE;

    if (blockIdx.x == 0) {
        bool bad = false;
        for (int p = tid; p < nprim; p += 1024) {
            float x0 = cp[p * 6 + 0], y0 = cp[p * 6 + 1];
            float x1 = cp[p * 6 + 2], y1 = cp[p * 6 + 3];
            float w = sw[p];
            float dx = __fsub_rn(x1, x0);
            float dy = __fsub_rn(y1, y0);
            float dd = __fadd_rn(__fmul_rn(dx, dx), __fmul_rn(dy, dy));
            float denom = fmaxf(dd, 1e-12f);
            double inv = 1.0 / (double)denom;
            unsigned wb = __float_as_uint(w);
            bool even = (wb & 1u) == 0u;
            float wn = __uint_as_float(wb + 1u);
            double md = 0.5 * ((double)w + (double)wn);
            double m2 = md * md;
            float Tf = (float)m2;
            if ((double)Tf > m2) Tf = __uint_as_float(__float_as_uint(Tf) - 1u);
            if (!even && (double)Tf == m2) Tf = __uint_as_float(__float_as_uint(Tf) - 1u);
            unsigned long long ib = __double_as_longlong(inv);
            packed2[p * 2 + 0] = make_float4(x0, y0, dx, dy);
            packed2[p * 2 + 1] = make_float4(Tf,
                                             __uint_as_float((unsigned)(ib & 0xffffffffull)),
                                             __uint_as_float((unsigned)(ib >> 32)),
                                             w);
            float opv = op[p];
            colors[p] = make_float4(fc[p * 3 + 0], fc[p * 3 + 1], fc[p * 3 + 2], opv);
            if (opv != 1.0f) bad = true;
        }
        if (bad) atomicOr(&sbad, 1);
        __syncthreads();
        if (tid == 0) flagp[0] = sbad;
    }
}

// ---------------------------------------------------------------------------
// Kernel 2: build 256x256 subgrid, exact capsule culling (f64 slab test of
// segment vs subcell rect dilated by w + 1e-5). Row: u16 cnt | 15 u16 (32 B).
// Unused entries are ZERO-FILLED so branchless group loads are safe.
// ---------------------------------------------------------------------------
__global__ __launch_bounds__(1024) void build_sub(const float4* __restrict__ packed2,
                                                  const int* __restrict__ etab,
                                                  unsigned short* __restrict__ subtab) {
    int t = blockIdx.x * 1024 + threadIdx.x;
    int parent = t >> 4;
    int sub = t & 15;
    int ix = parent >> 6, iy = parent & 63;
    int gx = ix * 4 + (sub >> 2), gy = iy * 4 + (sub & 3);
    double clx = (double)gx * (1.0 / 256.0);
    double chx = (double)(gx + 1) * (1.0 / 256.0);
    double cly = (double)gy * (1.0 / 256.0);
    double chy = (double)(gy + 1) * (1.0 / 256.0);
    const int* row = etab + (size_t)parent * EROW;
    int cnt = row[0];
    unsigned short* srow = subtab + (size_t)(gx * 256 + gy) * 16;
    int oc = 0;
    for (int s = 0; s < cnt; ++s) {
        int e = row[1 + s];
        float4 A = packed2[e * 2 + 0];
        float4 B = packed2[e * 2 + 1];
        double W = (double)B.w + 1e-5;
        double lx = clx - W, hx = chx + W, ly = cly - W, hy = chy + W;
        double ax = (double)A.x, ay = (double)A.y;
        double dx = (double)A.z, dy = (double)A.w;
        double t0 = 0.0, t1 = 1.0;
        bool ok = true;
        if (fabs(dx) > 1e-300) {
            double ta = (lx - ax) / dx, tb = (hx - ax) / dx;
            t0 = fmax(t0, fmin(ta, tb));
            t1 = fmin(t1, fmax(ta, tb));
        } else if (ax < lx || ax > hx) ok = false;
        if (ok) {
            if (fabs(dy) > 1e-300) {
                double ta = (ly - ay) / dy, tb = (hy - ay) / dy;
                t0 = fmax(t0, fmin(ta, tb));
                t1 = fmin(t1, fmax(ta, tb));
            } else if (ay < ly || ay > hy) ok = false;
        }
        if (ok && t0 <= t1) {
            if (oc < SCAP2) srow[1 + oc] = (unsigned short)e;
            ++oc;
        }
    }
    int filled = oc < SCAP2 ? oc : SCAP2;
    for (int k = filled; k < SCAP2; ++k) srow[1 + k] = 0;
    srow[0] = (oc <= SCAP2) ? (unsigned short)oc : (unsigned short)SENTV;
}

// sequential exact test (used on rare paths)
__device__ __forceinline__ void test_seq(int e, float px, float py, bool fast,
                                         int& win, float& cr, float& cg, float& cb,
                                         const float4* sA, const float4* sBsk,
                                         const float4* __restrict__ colors) {
    float4 A = sA[e];
    float4 Bv = sBsk[e + 4];
    CORE_EVAL(A, Bv);
    if (fast) {
        if (s2 <= Bv.x) win = e;
    } else {
        float4 C = colors[e];
        float a = (s2 <= Bv.x) ? C.w : 0.0f;
        float om = __fsub_rn(1.0f, a);
        cr = __fadd_rn(__fmul_rn(cr, om), __fmul_rn(C.x, a));
        cg = __fadd_rn(__fmul_rn(cg, om), __fmul_rn(C.y, a));
        cb = __fadd_rn(__fmul_rn(cb, om), __fmul_rn(C.z, a));
    }
}

// ---------------------------------------------------------------------------
// Kernel 3: render with explicit ILP. 2 pts/thread, 512-thread blocks.
// Fast path: branchless groups of 4 slots — 8 ds_read_b128 issued
// back-to-back per group, winner via predicated updates (no per-slot branch).
// ---------------------------------------------------------------------------
__global__ __launch_bounds__(512) void render_ilp(const float4* __restrict__ xs4,
                                                  const float4* __restrict__ packed2,
                                                  const float4* __restrict__ colors,
                                                  const int* __restrict__ etab,
                                                  const int* __restrict__ subtab,
                                                  const float* __restrict__ bg,
                                                  const int* __restrict__ flagp,
                                                  float* __restrict__ out,
                                                  int n, int nprim) {
    __shared__ float4 sA[MAXPRIM];
    __shared__ float4 sBsk[MAXPRIM + 4];

    int tid = threadIdx.x;
    long long g0 = (long long)blockIdx.x * 1024 + (long long)tid * 2;
    bool v0 = g0 < (long long)n, v1 = (g0 + 1) < (long long)n;

    float4 P = make_float4(0.f, 0.f, 0.f, 0.f);
    if (v1) {
        P = xs4[g0 >> 1];
    } else if (v0) {
        float2 t2 = ((const float2*)xs4)[g0];
        P.x = t2.x; P.y = t2.y;
    }
    float pxa[2] = {P.x, P.z};
    float pya[2] = {P.y, P.w};
    bool vs[2] = {v0, v1};
    int par[2] = {0, 0};
    int4 lo[2], hi[2];
    const int* srowp[2];
    lo[0] = lo[1] = make_int4(0, 0, 0, 0);
    hi[0] = hi[1] = make_int4(0, 0, 0, 0);
    srowp[0] = srowp[1] = subtab;

#pragma unroll
    for (int j = 0; j < 2; ++j) {
        if (vs[j]) {
            float px = pxa[j], py = pya[j];
            int ix = (int)__fmul_rn(px, (float)GRIDN);
            ix = min(max(ix, 0), GRIDN - 1);
            int iy = (int)__fmul_rn(py, (float)GRIDN);
            iy = min(max(iy, 0), GRIDN - 1);
            par[j] = ix * GRIDN + iy;
            int sx = (int)__fmul_rn(px, 256.0f) - ix * 4; sx = min(max(sx, 0), 3);
            int sy = (int)__fmul_rn(py, 256.0f) - iy * 4; sy = min(max(sy, 0), 3);
            const int* srow = subtab + (size_t)((ix * 4 + sx) * 256 + (iy * 4 + sy)) * 8;
            srowp[j] = srow;
            lo[j] = *(const int4*)srow;
            hi[j] = *(const int4*)(srow + 4);
        }
    }

    for (int t = tid; t < nprim; t += 512) {
        sA[t] = packed2[t * 2 + 0];
        sBsk[t + 4] = packed2[t * 2 + 1];
    }
    __syncthreads();

    bool fast = (flagp[0] == 0);
    float bgr = bg[0], bgg = bg[1], bgb = bg[2];
    float res[6];

// branchless 4-slot group: loads first (8 outstanding b128), predicated wins
#define FGRP4(basek, ea, eb, ec, ed)                                           \
    {                                                                          \
        float4 A0 = sA[ea], Q0 = sBsk[(ea) + 4];                               \
        float4 A1 = sA[eb], Q1 = sBsk[(eb) + 4];                               \
        float4 A2 = sA[ec], Q2 = sBsk[(ec) + 4];                               \
        float4 A3 = sA[ed], Q3 = sBsk[(ed) + 4];                               \
        { CORE_EVAL(A0, Q0); if (s2 <= Q0.x && (basek) + 0 < cnt) win = (ea); }\
        { CORE_EVAL(A1, Q1); if (s2 <= Q1.x && (basek) + 1 < cnt) win = (eb); }\
        { CORE_EVAL(A2, Q2); if (s2 <= Q2.x && (basek) + 2 < cnt) win = (ec); }\
        { CORE_EVAL(A3, Q3); if (s2 <= Q3.x && (basek) + 3 < cnt) win = (ed); }\
    }
#define FGRP3(basek, ea, eb, ec)                                               \
    {                                                                          \
        float4 A0 = sA[ea], Q0 = sBsk[(ea) + 4];                               \
        float4 A1 = sA[eb], Q1 = sBsk[(eb) + 4];                               \
        float4 A2 = sA[ec], Q2 = sBsk[(ec) + 4];                               \
        { CORE_EVAL(A0, Q0); if (s2 <= Q0.x && (basek) + 0 < cnt) win = (ea); }\
        { CORE_EVAL(A1, Q1); if (s2 <= Q1.x && (basek) + 1 < cnt) win = (eb); }\
        { CORE_EVAL(A2, Q2); if (s2 <= Q2.x && (basek) + 2 < cnt) win = (ec); }\
    }

#pragma unroll
    for (int j = 0; j < 2; ++j) {
        float px = pxa[j], py = pya[j];
        float cr = bgr, cg = bgg, cb = bgb;
        int win = -1;
        unsigned lx = (unsigned)lo[j].x, ly = (unsigned)lo[j].y;
        unsigned lz = (unsigned)lo[j].z, lw = (unsigned)lo[j].w;
        unsigned hxv = (unsigned)hi[j].x, hyv = (unsigned)hi[j].y;
        unsigned hzv = (unsigned)hi[j].z, hwv = (unsigned)hi[j].w;
        int cnt = vs[j] ? (int)(lx & 0xffffu) : 0;
        if (cnt != SENTV) {
            if (fast) {
                int e0 = (int)(lx >> 16), e1 = (int)(ly & 0xffffu);
                int e2 = (int)(ly >> 16), e3 = (int)(lz & 0xffffu);
                if (cnt > 0) FGRP4(0, e0, e1, e2, e3);
                if (cnt > 4) {
                    int e4 = (int)(lz >> 16), e5 = (int)(lw & 0xffffu);
                    int e6 = (int)(lw >> 16), e7 = (int)(hxv & 0xffffu);
                    FGRP4(4, e4, e5, e6, e7);
                }
                if (cnt > 8) {
                    int e8 = (int)(hxv >> 16), e9 = (int)(hyv & 0xffffu);
                    int e10 = (int)(hyv >> 16), e11 = (int)(hzv & 0xffffu);
                    FGRP4(8, e8, e9, e10, e11);
                }
                if (cnt > 12) {
                    int e12 = (int)(hzv >> 16), e13 = (int)(hwv & 0xffffu);
                    int e14 = (int)(hwv >> 16);
                    FGRP3(12, e12, e13, e14);
                }
            } else {
                const unsigned short* sr16 = (const unsigned short*)srowp[j];
                for (int s = 0; s < cnt; ++s)
                    test_seq((int)sr16[1 + s], px, py, false, win, cr, cg, cb,
                             sA, sBsk, colors);
            }
        } else {
            const int* prow = etab + (size_t)par[j] * EROW;
            int pcnt = prow[0];
            for (int s = 0; s < pcnt; ++s)
                test_seq(prow[1 + s], px, py, fast, win, cr, cg, cb,
                         sA, sBsk, colors);
        }
        if (fast && win >= 0) {
            float4 C = colors[win];
            cr = C.x; cg = C.y; cb = C.z;
        }
        res[j * 3 + 0] = cr;
        res[j * 3 + 1] = cg;
        res[j * 3 + 2] = cb;
    }
#undef FGRP4
#undef FGRP3

    float* ob = out + g0 * 3;
    if (v1) {
        *(float2*)(ob + 0) = make_float2(res[0], res[1]);
        *(float2*)(ob + 2) = make_float2(res[2], res[3]);
        *(float2*)(ob + 4) = make_float2(res[4], res[5]);
    } else if (v0) {
        ob[0] = res[0]; ob[1] = res[1]; ob[2] = res[2];
    }
}

// ---------------------------------------------------------------------------
// Fallback render (round-4 style) if ws_size too small for the subgrid.
// ---------------------------------------------------------------------------
__global__ __launch_bounds__(1024) void render_fb(const float2* __restrict__ xs,
                                                  const float4* __restrict__ packed2,
                                                  const float4* __restrict__ colors,
                                                  const int* __restrict__ etab,
                                                  const float* __restrict__ bg,
                                                  float* __restrict__ out, int n, int nprim) {
    __shared__ float4 sA[MAXPRIM];
    __shared__ float4 sBsk[MAXPRIM + 4];
    __shared__ int sflag;
    if (threadIdx.x == 0) sflag = 0;
    __syncthreads();

    int i = blockIdx.x * 1024 + threadIdx.x;
    bool valid = i < n;
    float px = 0.0f, py = 0.0f;
    int row = 0;
    int4 c0 = make_int4(0, 0, 0, 0), c1 = make_int4(0, 0, 0, 0);
    if (valid) {
        float2 pxy = xs[i];
        px = pxy.x; py = pxy.y;
        int ix = (int)__fmul_rn(px, (float)GRIDN);
        ix = min(max(ix, 0), GRIDN - 1);
        int iy = (int)__fmul_rn(py, (float)GRIDN);
        iy = min(max(iy, 0), GRIDN - 1);
        row = (ix * GRIDN + iy) * EROW;
        c0 = *(const int4*)(etab + row);
        c1 = *(const int4*)(etab + row + 4);
    }
    for (int t = threadIdx.x; t < nprim; t += 1024) {
        sA[t] = packed2[t * 2 + 0];
        sBsk[t + 4] = packed2[t * 2 + 1];
        if (colors[t].w != 1.0f) sflag = 1;
    }
    __syncthreads();
    int cnt = valid ? c0.x : 0;
    float cr = bg[0], cg = bg[1], cb = bg[2];
    int win = -1;
    bool fast = (sflag == 0);
    if (cnt > 0) test_seq(c0.y, px, py, fast, win, cr, cg, cb, sA, sBsk, colors);
    if (cnt > 1) test_seq(c0.z, px, py, fast, win, cr, cg, cb, sA, sBsk, colors);
    if (cnt > 2) test_seq(c0.w, px, py, fast, win, cr, cg, cb, sA, sBsk, colors);
    if (cnt > 3) test_seq(c1.x, px, py, fast, win, cr, cg, cb, sA, sBsk, colors);
    if (cnt > 4) test_seq(c1.y, px, py, fast, win, cr, cg, cb, sA, sBsk, colors);
    if (cnt > 5) test_seq(c1.z, px, py, fast, win, cr, cg, cb, sA, sBsk, colors);
    if (cnt > 6) test_seq(c1.w, px, py, fast, win, cr, cg, cb, sA, sBsk, colors);
    for (int base = 7; base < cnt; base += 4) {
        int4 c = *(const int4*)(etab + row + 1 + base);
        if (base + 0 < cnt) test_seq(c.x, px, py, fast, win, cr, cg, cb, sA, sBsk, colors);
        if (base + 1 < cnt) test_seq(c.y, px, py, fast, win, cr, cg, cb, sA, sBsk, colors);
        if (base + 2 < cnt) test_seq(c.z, px, py, fast, win, cr, cg, cb, sA, sBsk, colors);
        if (base + 3 < cnt) test_seq(c.w, px, py, fast, win, cr, cg, cb, sA, sBsk, colors);
    }
    if (valid) {
        if (fast && win >= 0) {
            float4 C = colors[win];
            cr = C.x; cg = C.y; cb = C.z;
        }
        out[(size_t)i * 3 + 0] = cr;
        out[(size_t)i * 3 + 1] = cg;
        out[(size_t)i * 3 + 2] = cb;
    }
}

extern "C" void kernel_launch(void* const* d_in, const int* in_sizes, int n_in,
                              void* d_out, int out_size, void* d_ws, size_t ws_size,
                              hipStream_t stream) {
    const float* x  = (const float*)d_in[0];
    const float* cp = (const float*)d_in[1];
    const float* sw = (const float*)d_in[2];
    const float* fc = (const float*)d_in[3];
    const float* op = (const float*)d_in[4];
    const float* bg = (const float*)d_in[5];
    float* out = (float*)d_out;

    int npts  = in_sizes[0] / 2;
    int nprim = in_sizes[2];

    char* ws = (char*)d_ws;
    float4* packed2 = (float4*)(ws + WS_PACKED2);
    float4* colors  = (float4*)(ws + WS_COLORS);
    int* etab       = (int*)(ws + WS_ETAB);
    int* flagp      = (int*)(ws + WS_FLAG);
    unsigned short* subtab = (unsigned short*)(ws + WS_SUBTAB);

    size_t need = (size_t)WS_SUBTAB + 65536u * 32u;
    bool use_sub = (ws_size >= need);

    prep<<<GRIDN * GRIDN / 16, 1024, 0, stream>>>(cp, sw, fc, op, packed2, colors,
                                                  etab, flagp, nprim);
    if (use_sub) {
        build_sub<<<64, 1024, 0, stream>>>(packed2, etab, subtab);
        int nblk = (npts + 1023) / 1024;
        render_ilp<<<nblk, 512, 0, stream>>>((const float4*)x, packed2, colors,
                                             etab, (const int*)subtab, bg, flagp,
                                             out, npts, nprim);
    } else {
        render_fb<<<(npts + 1023) / 1024, 1024, 0, stream>>>((const float2*)x, packed2,
                                                             colors, etab, bg, out,
                                                             npts, nprim);
    }
}

// Round 11
// 53.052 us; speedup vs baseline: 1.4412x; 1.1037x over previous
//
#include <hip/hip_runtime.h>
#include <math.h>

#define GRIDN 64
#define MAXE 32
#define MAXPRIM 1024
#define EROW 36        // parent row: [cnt, e0..e31, pad x3]
#define SCAP2 15
#define SENTV 0xFFFF

// workspace layout (bytes)
#define WS_PACKED2   0u            // 1024*32
#define WS_COLORS    32768u        // 1024*16
#define WS_ETAB      49152u        // 4096*36*4 = 589824 -> ends 638976
#define WS_FLAG      638976u       // 4 B: nonzero if any opacity != 1
#define WS_SUBTAB    655360u       // 65536*32 = 2 MB -> ends 2752512

#define SGB __builtin_amdgcn_sched_group_barrier
// LLVM SchedGroupMask: VALU=0x2, DS_READ=0x100

// exact core: t = rn(td/denom) (double-recip mul), s2 <= Tf <=> rn(sqrt(s2)) <= w
#define CORE_EVAL(A, Bv)                                                         \
    float relx = __fsub_rn(px, A.x);                                             \
    float rely = __fsub_rn(py, A.y);                                             \
    float td = __fadd_rn(__fmul_rn(relx, A.z), __fmul_rn(rely, A.w));            \
    double inv = __hiloint2double(__float_as_int(Bv.z), __float_as_int(Bv.y));   \
    float tt = (float)((double)td * inv);                                        \
    tt = fminf(fmaxf(tt, 0.0f), 1.0f);                                           \
    float qx = __fsub_rn(relx, __fmul_rn(tt, A.z));                              \
    float qy = __fsub_rn(rely, __fmul_rn(tt, A.w));                              \
    float s2 = __fadd_rn(__fmul_rn(qx, qx), __fmul_rn(qy, qy));

// ---------------------------------------------------------------------------
// Kernel 1 (fused): parent grid build + subgrid prune + (block 0) prim pack.
// Phase A: stage seg/aabb/width in LDS.  Phase B: 16 waves build 16 parent
// rows (global etab + LDS copy).  Phase C: threads 0-255 prune the 256
// subcells of this block's parents (exact f64 capsule-vs-dilated-rect slab
// test), zero-filling unused entries.  Phase D: block 0 packs prim records.
// ---------------------------------------------------------------------------
__global__ __launch_bounds__(1024) void prep2(const float* __restrict__ cp,
                                              const float* __restrict__ sw,
                                              const float* __restrict__ fc,
                                              const float* __restrict__ op,
                                              float4* __restrict__ packed2,
                                              float4* __restrict__ colors,
                                              int* __restrict__ etab,
                                              int* __restrict__ flagp,
                                              unsigned short* __restrict__ subtab,
                                              int nprim) {
    __shared__ float4 saabb[MAXPRIM];
    __shared__ float4 sseg[MAXPRIM];   // (x0, y0, dx, dy)
    __shared__ float  sww[MAXPRIM];
    __shared__ int    srows[16][EROW];
    __shared__ int    sbad;
    int tid = threadIdx.x;
    if (tid == 0) sbad = 0;
    for (int p = tid; p < nprim; p += 1024) {
        float x0 = cp[p * 6 + 0], y0 = cp[p * 6 + 1];
        float x1 = cp[p * 6 + 2], y1 = cp[p * 6 + 3];
        float w = sw[p];
        saabb[p] = make_float4(__fsub_rn(fminf(x0, x1), w), __fadd_rn(fmaxf(x0, x1), w),
                               __fsub_rn(fminf(y0, y1), w), __fadd_rn(fmaxf(y0, y1), w));
        sseg[p] = make_float4(x0, y0, __fsub_rn(x1, x0), __fsub_rn(y1, y0));
        sww[p] = w;
    }
    __syncthreads();

    // ---- phase B: parent rows (one wave per parent cell) ----
    int wid = tid >> 6, lane = tid & 63;
    int cell = blockIdx.x * 16 + wid;
    {
        int ixc = cell >> 6, iyc = cell & 63;
        float lox = (float)ixc * (1.0f / GRIDN);
        float hix = (float)(ixc + 1) * (1.0f / GRIDN);
        float loy = (float)iyc * (1.0f / GRIDN);
        float hiy = (float)(iyc + 1) * (1.0f / GRIDN);
        int total = 0;
        int* row = etab + (size_t)cell * EROW;
        for (int base = 0; base < nprim; base += 64) {
            int p = base + lane;
            bool ov = false;
            if (p < nprim) {
                float4 bb = saabb[p];
                ov = (bb.x < hix) && (bb.y >= lox) && (bb.z < hiy) && (bb.w >= loy);
            }
            unsigned long long m = __ballot(ov);
            if (ov) {
                int pos = total + (int)__popcll(m & ((1ull << lane) - 1ull));
                if (pos < MAXE) { row[1 + pos] = p; srows[wid][1 + pos] = p; }
            }
            total += (int)__popcll(m);
        }
        if (lane == 0) {
            int c = total < MAXE ? total : MAXE;
            row[0] = c;
            srows[wid][0] = c;
        }
    }
    __syncthreads();

    // ---- phase C: subcell pruning (threads 0-255, one subcell each) ----
    if (tid < 256) {
        int lp = tid >> 4;                 // local parent 0..15
        int sub = tid & 15;
        int pcell = blockIdx.x * 16 + lp;
        int ix = pcell >> 6, iy = pcell & 63;
        int gx = ix * 4 + (sub >> 2), gy = iy * 4 + (sub & 3);
        double clx = (double)gx * (1.0 / 256.0);
        double chx = (double)(gx + 1) * (1.0 / 256.0);
        double cly = (double)gy * (1.0 / 256.0);
        double chy = (double)(gy + 1) * (1.0 / 256.0);
        int cnt = srows[lp][0];
        unsigned short* srow = subtab + (size_t)(gx * 256 + gy) * 16;
        int oc = 0;
        for (int s = 0; s < cnt; ++s) {
            int e = srows[lp][1 + s];
            float4 A = sseg[e];
            double W = (double)sww[e] + 1e-5;
            double lx = clx - W, hx = chx + W, ly = cly - W, hy = chy + W;
            double ax = (double)A.x, ay = (double)A.y;
            double dx = (double)A.z, dy = (double)A.w;
            double t0 = 0.0, t1 = 1.0;
            bool ok = true;
            if (fabs(dx) > 1e-300) {
                double ta = (lx - ax) / dx, tb = (hx - ax) / dx;
                t0 = fmax(t0, fmin(ta, tb));
                t1 = fmin(t1, fmax(ta, tb));
            } else if (ax < lx || ax > hx) ok = false;
            if (ok) {
                if (fabs(dy) > 1e-300) {
                    double ta = (ly - ay) / dy, tb = (hy - ay) / dy;
                    t0 = fmax(t0, fmin(ta, tb));
                    t1 = fmin(t1, fmax(ta, tb));
                } else if (ay < ly || ay > hy) ok = false;
            }
            if (ok && t0 <= t1) {
                if (oc < SCAP2) srow[1 + oc] = (unsigned short)e;
                ++oc;
            }
        }
        int filled = oc < SCAP2 ? oc : SCAP2;
        for (int k = filled; k < SCAP2; ++k) srow[1 + k] = 0;
        srow[0] = (oc <= SCAP2) ? (unsigned short)oc : (unsigned short)SENTV;
    }

    // ---- phase D: prim pack (block 0) ----
    if (blockIdx.x == 0) {
        bool bad = false;
        for (int p = tid; p < nprim; p += 1024) {
            float x0 = cp[p * 6 + 0], y0 = cp[p * 6 + 1];
            float x1 = cp[p * 6 + 2], y1 = cp[p * 6 + 3];
            float w = sw[p];
            float dx = __fsub_rn(x1, x0);
            float dy = __fsub_rn(y1, y0);
            float dd = __fadd_rn(__fmul_rn(dx, dx), __fmul_rn(dy, dy));
            float denom = fmaxf(dd, 1e-12f);
            double inv = 1.0 / (double)denom;
            unsigned wb = __float_as_uint(w);
            bool even = (wb & 1u) == 0u;
            float wn = __uint_as_float(wb + 1u);
            double md = 0.5 * ((double)w + (double)wn);
            double m2 = md * md;
            float Tf = (float)m2;
            if ((double)Tf > m2) Tf = __uint_as_float(__float_as_uint(Tf) - 1u);
            if (!even && (double)Tf == m2) Tf = __uint_as_float(__float_as_uint(Tf) - 1u);
            unsigned long long ib = __double_as_longlong(inv);
            packed2[p * 2 + 0] = make_float4(x0, y0, dx, dy);
            packed2[p * 2 + 1] = make_float4(Tf,
                                             __uint_as_float((unsigned)(ib & 0xffffffffull)),
                                             __uint_as_float((unsigned)(ib >> 32)),
                                             w);
            float opv = op[p];
            colors[p] = make_float4(fc[p * 3 + 0], fc[p * 3 + 1], fc[p * 3 + 2], opv);
            if (opv != 1.0f) bad = true;
        }
        if (bad) atomicOr(&sbad, 1);
        __syncthreads();
        if (tid == 0) flagp[0] = sbad;
    }
}

// sequential exact test (rare paths)
__device__ __forceinline__ void test_seq(int e, float px, float py, bool fast,
                                         int& win, float& cr, float& cg, float& cb,
                                         const float4* sA, const float4* sBsk,
                                         const float4* __restrict__ colors) {
    float4 A = sA[e];
    float4 Bv = sBsk[e + 4];
    CORE_EVAL(A, Bv);
    if (fast) {
        if (s2 <= Bv.x) win = e;
    } else {
        float4 C = colors[e];
        float a = (s2 <= Bv.x) ? C.w : 0.0f;
        float om = __fsub_rn(1.0f, a);
        cr = __fadd_rn(__fmul_rn(cr, om), __fmul_rn(C.x, a));
        cg = __fadd_rn(__fmul_rn(cg, om), __fmul_rn(C.y, a));
        cb = __fadd_rn(__fmul_rn(cb, om), __fmul_rn(C.z, a));
    }
}

// ---------------------------------------------------------------------------
// Kernel 2: render. 2 pts/thread, 512-thread blocks. Branchless 4-slot
// groups with sched_group_barrier pinning {8 x DS_READ} -> {VALU cluster}
// so the 8 LDS gathers stay in flight together (compiler otherwise
// serializes them: VGPR_Count=32 evidence, rounds 9-10).
// ---------------------------------------------------------------------------
__global__ __launch_bounds__(512) void render_ilp(const float4* __restrict__ xs4,
                                                  const float4* __restrict__ packed2,
                                                  const float4* __restrict__ colors,
                                                  const int* __restrict__ etab,
                                                  const int* __restrict__ subtab,
                                                  const float* __restrict__ bg,
                                                  const int* __restrict__ flagp,
                                                  float* __restrict__ out,
                                                  int n, int nprim) {
    __shared__ float4 sA[MAXPRIM];
    __shared__ float4 sBsk[MAXPRIM + 4];

    int tid = threadIdx.x;
    long long g0 = (long long)blockIdx.x * 1024 + (long long)tid * 2;
    bool v0 = g0 < (long long)n, v1 = (g0 + 1) < (long long)n;

    float4 P = make_float4(0.f, 0.f, 0.f, 0.f);
    if (v1) {
        P = xs4[g0 >> 1];
    } else if (v0) {
        float2 t2 = ((const float2*)xs4)[g0];
        P.x = t2.x; P.y = t2.y;
    }
    float pxa[2] = {P.x, P.z};
    float pya[2] = {P.y, P.w};
    bool vs[2] = {v0, v1};
    int par[2] = {0, 0};
    int4 lo[2], hi[2];
    const int* srowp[2];
    lo[0] = lo[1] = make_int4(0, 0, 0, 0);
    hi[0] = hi[1] = make_int4(0, 0, 0, 0);
    srowp[0] = srowp[1] = subtab;

#pragma unroll
    for (int j = 0; j < 2; ++j) {
        if (vs[j]) {
            float px = pxa[j], py = pya[j];
            int ix = (int)__fmul_rn(px, (float)GRIDN);
            ix = min(max(ix, 0), GRIDN - 1);
            int iy = (int)__fmul_rn(py, (float)GRIDN);
            iy = min(max(iy, 0), GRIDN - 1);
            par[j] = ix * GRIDN + iy;
            int sx = (int)__fmul_rn(px, 256.0f) - ix * 4; sx = min(max(sx, 0), 3);
            int sy = (int)__fmul_rn(py, 256.0f) - iy * 4; sy = min(max(sy, 0), 3);
            const int* srow = subtab + (size_t)((ix * 4 + sx) * 256 + (iy * 4 + sy)) * 8;
            srowp[j] = srow;
            lo[j] = *(const int4*)srow;
            hi[j] = *(const int4*)(srow + 4);
        }
    }

    for (int t = tid; t < nprim; t += 512) {
        sA[t] = packed2[t * 2 + 0];
        sBsk[t + 4] = packed2[t * 2 + 1];
    }
    __syncthreads();

    bool fast = (flagp[0] == 0);
    float bgr = bg[0], bgg = bg[1], bgb = bg[2];
    float res[6];

// branchless 4-slot group: 8 ds_read_b128 clustered via sched_group_barrier,
// then the VALU block; winner via predicated updates.
#define FGRP4(basek, ea, eb, ec, ed)                                           \
    {                                                                          \
        float4 A0 = sA[ea], Q0 = sBsk[(ea) + 4];                               \
        float4 A1 = sA[eb], Q1 = sBsk[(eb) + 4];                               \
        float4 A2 = sA[ec], Q2 = sBsk[(ec) + 4];                               \
        float4 A3 = sA[ed], Q3 = sBsk[(ed) + 4];                               \
        { CORE_EVAL(A0, Q0); if (s2 <= Q0.x && (basek) + 0 < cnt) win = (ea); }\
        { CORE_EVAL(A1, Q1); if (s2 <= Q1.x && (basek) + 1 < cnt) win = (eb); }\
        { CORE_EVAL(A2, Q2); if (s2 <= Q2.x && (basek) + 2 < cnt) win = (ec); }\
        { CORE_EVAL(A3, Q3); if (s2 <= Q3.x && (basek) + 3 < cnt) win = (ed); }\
        SGB(0x100, 8, 0);   /* 8 x DS_READ first */                            \
        SGB(0x002, 80, 0);  /* then the VALU cluster */                        \
    }
#define FGRP3(basek, ea, eb, ec)                                               \
    {                                                                          \
        float4 A0 = sA[ea], Q0 = sBsk[(ea) + 4];                               \
        float4 A1 = sA[eb], Q1 = sBsk[(eb) + 4];                               \
        float4 A2 = sA[ec], Q2 = sBsk[(ec) + 4];                               \
        { CORE_EVAL(A0, Q0); if (s2 <= Q0.x && (basek) + 0 < cnt) win = (ea); }\
        { CORE_EVAL(A1, Q1); if (s2 <= Q1.x && (basek) + 1 < cnt) win = (eb); }\
        { CORE_EVAL(A2, Q2); if (s2 <= Q2.x && (basek) + 2 < cnt) win = (ec); }\
        SGB(0x100, 6, 0);                                                      \
        SGB(0x002, 60, 0);                                                     \
    }

#pragma unroll
    for (int j = 0; j < 2; ++j) {
        float px = pxa[j], py = pya[j];
        float cr = bgr, cg = bgg, cb = bgb;
        int win = -1;
        unsigned lx = (unsigned)lo[j].x, ly = (unsigned)lo[j].y;
        unsigned lz = (unsigned)lo[j].z, lw = (unsigned)lo[j].w;
        unsigned hxv = (unsigned)hi[j].x, hyv = (unsigned)hi[j].y;
        unsigned hzv = (unsigned)hi[j].z, hwv = (unsigned)hi[j].w;
        int cnt = vs[j] ? (int)(lx & 0xffffu) : 0;
        if (cnt != SENTV) {
            if (fast) {
                int e0 = (int)(lx >> 16), e1 = (int)(ly & 0xffffu);
                int e2 = (int)(ly >> 16), e3 = (int)(lz & 0xffffu);
                if (cnt > 0) FGRP4(0, e0, e1, e2, e3);
                if (cnt > 4) {
                    int e4 = (int)(lz >> 16), e5 = (int)(lw & 0xffffu);
                    int e6 = (int)(lw >> 16), e7 = (int)(hxv & 0xffffu);
                    FGRP4(4, e4, e5, e6, e7);
                }
                if (cnt > 8) {
                    int e8 = (int)(hxv >> 16), e9 = (int)(hyv & 0xffffu);
                    int e10 = (int)(hyv >> 16), e11 = (int)(hzv & 0xffffu);
                    FGRP4(8, e8, e9, e10, e11);
                }
                if (cnt > 12) {
                    int e12 = (int)(hzv >> 16), e13 = (int)(hwv & 0xffffu);
                    int e14 = (int)(hwv >> 16);
                    FGRP3(12, e12, e13, e14);
                }
            } else {
                const unsigned short* sr16 = (const unsigned short*)srowp[j];
                for (int s = 0; s < cnt; ++s)
                    test_seq((int)sr16[1 + s], px, py, false, win, cr, cg, cb,
                             sA, sBsk, colors);
            }
        } else {
            const int* prow = etab + (size_t)par[j] * EROW;
            int pcnt = prow[0];
            for (int s = 0; s < pcnt; ++s)
                test_seq(prow[1 + s], px, py, fast, win, cr, cg, cb,
                         sA, sBsk, colors);
        }
        if (fast && win >= 0) {
            float4 C = colors[win];
            cr = C.x; cg = C.y; cb = C.z;
        }
        res[j * 3 + 0] = cr;
        res[j * 3 + 1] = cg;
        res[j * 3 + 2] = cb;
    }
#undef FGRP4
#undef FGRP3

    float* ob = out + g0 * 3;
    if (v1) {
        *(float2*)(ob + 0) = make_float2(res[0], res[1]);
        *(float2*)(ob + 2) = make_float2(res[2], res[3]);
        *(float2*)(ob + 4) = make_float2(res[4], res[5]);
    } else if (v0) {
        ob[0] = res[0]; ob[1] = res[1]; ob[2] = res[2];
    }
}

// ---------------------------------------------------------------------------
// Fallback render (round-4 style) if ws_size too small for the subgrid.
// ---------------------------------------------------------------------------
__global__ __launch_bounds__(1024) void render_fb(const float2* __restrict__ xs,
                                                  const float4* __restrict__ packed2,
                                                  const float4* __restrict__ colors,
                                                  const int* __restrict__ etab,
                                                  const float* __restrict__ bg,
                                                  float* __restrict__ out, int n, int nprim) {
    __shared__ float4 sA[MAXPRIM];
    __shared__ float4 sBsk[MAXPRIM + 4];
    __shared__ int sflag;
    if (threadIdx.x == 0) sflag = 0;
    __syncthreads();

    int i = blockIdx.x * 1024 + threadIdx.x;
    bool valid = i < n;
    float px = 0.0f, py = 0.0f;
    int row = 0;
    int4 c0 = make_int4(0, 0, 0, 0), c1 = make_int4(0, 0, 0, 0);
    if (valid) {
        float2 pxy = xs[i];
        px = pxy.x; py = pxy.y;
        int ix = (int)__fmul_rn(px, (float)GRIDN);
        ix = min(max(ix, 0), GRIDN - 1);
        int iy = (int)__fmul_rn(py, (float)GRIDN);
        iy = min(max(iy, 0), GRIDN - 1);
        row = (ix * GRIDN + iy) * EROW;
        c0 = *(const int4*)(etab + row);
        c1 = *(const int4*)(etab + row + 4);
    }
    for (int t = threadIdx.x; t < nprim; t += 1024) {
        sA[t] = packed2[t * 2 + 0];
        sBsk[t + 4] = packed2[t * 2 + 1];
        if (colors[t].w != 1.0f) sflag = 1;
    }
    __syncthreads();
    int cnt = valid ? c0.x : 0;
    float cr = bg[0], cg = bg[1], cb = bg[2];
    int win = -1;
    bool fast = (sflag == 0);
    if (cnt > 0) test_seq(c0.y, px, py, fast, win, cr, cg, cb, sA, sBsk, colors);
    if (cnt > 1) test_seq(c0.z, px, py, fast, win, cr, cg, cb, sA, sBsk, colors);
    if (cnt > 2) test_seq(c0.w, px, py, fast, win, cr, cg, cb, sA, sBsk, colors);
    if (cnt > 3) test_seq(c1.x, px, py, fast, win, cr, cg, cb, sA, sBsk, colors);
    if (cnt > 4) test_seq(c1.y, px, py, fast, win, cr, cg, cb, sA, sBsk, colors);
    if (cnt > 5) test_seq(c1.z, px, py, fast, win, cr, cg, cb, sA, sBsk, colors);
    if (cnt > 6) test_seq(c1.w, px, py, fast, win, cr, cg, cb, sA, sBsk, colors);
    for (int base = 7; base < cnt; base += 4) {
        int4 c = *(const int4*)(etab + row + 1 + base);
        if (base + 0 < cnt) test_seq(c.x, px, py, fast, win, cr, cg, cb, sA, sBsk, colors);
        if (base + 1 < cnt) test_seq(c.y, px, py, fast, win, cr, cg, cb, sA, sBsk, colors);
        if (base + 2 < cnt) test_seq(c.z, px, py, fast, win, cr, cg, cb, sA, sBsk, colors);
        if (base + 3 < cnt) test_seq(c.w, px, py, fast, win, cr, cg, cb, sA, sBsk, colors);
    }
    if (valid) {
        if (fast && win >= 0) {
            float4 C = colors[win];
            cr = C.x; cg = C.y; cb = C.z;
        }
        out[(size_t)i * 3 + 0] = cr;
        out[(size_t)i * 3 + 1] = cg;
        out[(size_t)i * 3 + 2] = cb;
    }
}

extern "C" void kernel_launch(void* const* d_in, const int* in_sizes, int n_in,
                              void* d_out, int out_size, void* d_ws, size_t ws_size,
                              hipStream_t stream) {
    const float* x  = (const float*)d_in[0];
    const float* cp = (const float*)d_in[1];
    const float* sw = (const float*)d_in[2];
    const float* fc = (const float*)d_in[3];
    const float* op = (const float*)d_in[4];
    const float* bg = (const float*)d_in[5];
    float* out = (float*)d_out;

    int npts  = in_sizes[0] / 2;
    int nprim = in_sizes[2];

    char* ws = (char*)d_ws;
    float4* packed2 = (float4*)(ws + WS_PACKED2);
    float4* colors  = (float4*)(ws + WS_COLORS);
    int* etab       = (int*)(ws + WS_ETAB);
    int* flagp      = (int*)(ws + WS_FLAG);
    unsigned short* subtab = (unsigned short*)(ws + WS_SUBTAB);

    size_t need = (size_t)WS_SUBTAB + 65536u * 32u;
    bool use_sub = (ws_size >= need);

    if (use_sub) {
        prep2<<<GRIDN * GRIDN / 16, 1024, 0, stream>>>(cp, sw, fc, op, packed2, colors,
                                                       etab, flagp, subtab, nprim);
        int nblk = (npts + 1023) / 1024;
        render_ilp<<<nblk, 512, 0, stream>>>((const float4*)x, packed2, colors,
                                             etab, (const int*)subtab, bg, flagp,
                                             out, npts, nprim);
    } else {
        prep2<<<GRIDN * GRIDN / 16, 1024, 0, stream>>>(cp, sw, fc, op, packed2, colors,
                                                       etab, flagp, subtab, nprim);
        render_fb<<<(npts + 1023) / 1024, 1024, 0, stream>>>((const float2*)x, packed2,
                                                             colors, etab, bg, out,
                                                             npts, nprim);
    }
}